// Round 1
// baseline (418.240 us; speedup 1.0000x reference)
//
#include <hip/hip_runtime.h>
#include <hip/hip_bf16.h>
#include <stdint.h>

#define NIMG 32
#define CHN 256       // in & out channels
#define HW 56
#define PH 58         // padded spatial
#define XP_ELEMS ((size_t)NIMG*PH*PH*CHN)     // 27,557,888 bf16
#define WT_ELEMS ((size_t)9*CHN*CHN)          // 589,824 bf16
#define OUT_ELEMS ((size_t)NIMG*CHN*HW*HW)    // 25,690,112

typedef __attribute__((ext_vector_type(8))) short short8;
typedef __attribute__((ext_vector_type(4))) float floatx4;

#define GLDS16(gp, lp) __builtin_amdgcn_global_load_lds( \
    (const __attribute__((address_space(1))) void*)(gp), \
    (__attribute__((address_space(3))) void*)(lp), 16, 0, 0)

__device__ inline unsigned short f2bf(float f) {
    union { float f; uint32_t u; } v; v.f = f;
    uint32_t u = v.u;
    return (unsigned short)((u + 0x7FFFu + ((u >> 16) & 1u)) >> 16);  // RNE
}

// ---- Kernel 1: weights (flat OIHW fp32) -> sign() bf16, layout [rs][ko][c] ----
__global__ void wprep(const float* __restrict__ wflat, unsigned short* __restrict__ Wt) {
    int idx = blockIdx.x * 256 + threadIdx.x;          // < 589824
    float w = wflat[idx];
    unsigned short b = (w > 0.f) ? 0x3F80u : (w < 0.f ? 0xBF80u : 0u);
    int ko  = idx / 2304;
    int rem = idx - ko * 2304;
    int c   = rem / 9;
    int rs  = rem - c * 9;
    Wt[((size_t)rs * CHN + ko) * CHN + c] = b;
}

// ---- Kernel 2: x NCHW fp32 -> padded NHWC bf16 (halo pre-zeroed by memset) ----
__global__ void xprep(const float* __restrict__ x, unsigned short* __restrict__ Xp) {
    __shared__ unsigned short tile[56 * 264];          // pitch 264 => 16B-aligned rows
    int b = blockIdx.x;                                 // 32*56 blocks: one (n,h) row
    int n = b / 56, h = b - n * 56;
    const float* xr = x + ((size_t)n * CHN) * (HW*HW) + h * HW;  // [c*3136 + w]
    int tid = threadIdx.x;
    #pragma unroll 4
    for (int it = 0; it < 56; ++it) {
        int i = it * 256 + tid;                         // 0..14335 over (c,w)
        int c = i / 56, w = i - c * 56;
        tile[w * 264 + c] = f2bf(xr[c * 3136 + w]);
    }
    __syncthreads();
    unsigned short* op = Xp + (((size_t)n * PH + (h + 1)) * PH + 1) * CHN;  // Xp[n][h+1][1][0]
    #pragma unroll
    for (int it = 0; it < 7; ++it) {
        int chunk = it * 256 + tid;                     // 0..1791
        int w = chunk >> 5, c0 = (chunk & 31) * 8;
        short8 v = *(const short8*)&tile[w * 264 + c0];
        *(short8*)&op[w * 256 + c0] = v;                // fully contiguous per block
    }
}

// ---- Kernel 3: implicit GEMM, 128x128 tile, 4 waves, BK=32, m97 structure ----
__global__ void __launch_bounds__(256)
bconv_mfma(const unsigned short* __restrict__ Xp, const unsigned short* __restrict__ Wt,
           const float* __restrict__ sf, float* __restrict__ out) {
    __shared__ unsigned short Alds[128 * 32];
    __shared__ unsigned short Blds[128 * 32];
    const int tid  = threadIdx.x;
    const int lane = tid & 63, wv = tid >> 6;
    const int wm = wv >> 1, wn = wv & 1;
    const int bid = blockIdx.x;
    const int nt = bid & 1, mt = bid >> 1;              // 2 N-tiles x 784 M-tiles

    // staging source addresses (per lane): row = i*64 + wv*16 + lane/4, cc = (lane&3)*8
    const int cc = (lane & 3) * 8;
    const int arow0 = wv * 16 + (lane >> 2);
    const unsigned short* gA[2];
    const unsigned short* gB[2];
    #pragma unroll
    for (int i = 0; i < 2; ++i) {
        int p  = mt * 128 + i * 64 + arow0;             // flattened (n,h,w) position
        int n  = p / 3136;
        int hw = p - n * 3136;
        int h  = hw / 56, w = hw - h * 56;
        gA[i] = Xp + (((size_t)n * PH + h) * PH + w) * CHN + cc;
        int ko = nt * 128 + i * 64 + arow0;
        gB[i] = Wt + (size_t)ko * CHN + cc;
    }
    unsigned short* lA0 = Alds + wv * 512;
    unsigned short* lA1 = Alds + 2048 + wv * 512;
    unsigned short* lB0 = Blds + wv * 512;
    unsigned short* lB1 = Blds + 2048 + wv * 512;

    floatx4 acc[4][4];
    #pragma unroll
    for (int m = 0; m < 4; ++m)
        #pragma unroll
        for (int n = 0; n < 4; ++n) acc[m][n] = (floatx4){0.f, 0.f, 0.f, 0.f};

    const int rsOff[9] = {0, 256, 512, 58*256, 58*256+256, 58*256+512,
                          116*256, 116*256+256, 116*256+512};

    for (int rs = 0; rs < 9; ++rs) {
        const unsigned short* a0 = gA[0] + rsOff[rs];
        const unsigned short* a1 = gA[1] + rsOff[rs];
        const unsigned short* b0 = gB[0] + rs * 65536;
        const unsigned short* b1 = gB[1] + rs * 65536;
        for (int c0 = 0; c0 < 256; c0 += 32) {
            GLDS16(a0 + c0, lA0);
            GLDS16(a1 + c0, lA1);
            GLDS16(b0 + c0, lB0);
            GLDS16(b1 + c0, lB1);
            __syncthreads();                            // drains vmcnt -> LDS ready
            const int lrow = lane & 15, lk = (lane >> 4) * 8;
            short8 af[4], bf[4];
            #pragma unroll
            for (int m = 0; m < 4; ++m)
                af[m] = *(const short8*)&Alds[(wm * 64 + m * 16 + lrow) * 32 + lk];
            #pragma unroll
            for (int n = 0; n < 4; ++n)
                bf[n] = *(const short8*)&Blds[(wn * 64 + n * 16 + lrow) * 32 + lk];
            #pragma unroll
            for (int m = 0; m < 4; ++m)
                #pragma unroll
                for (int n = 0; n < 4; ++n)
                    acc[m][n] = __builtin_amdgcn_mfma_f32_16x16x32_bf16(af[m], bf[n], acc[m][n], 0, 0, 0);
            __syncthreads();                            // safe to overwrite LDS
        }
    }

    // epilogue: fuse per-channel scale, scatter NHW,ko -> NCHW
    const int lrow = lane & 15, lq = lane >> 4;
    #pragma unroll
    for (int n = 0; n < 4; ++n) {
        int ko = nt * 128 + wn * 64 + n * 16 + lrow;
        float sc = sf[ko];
        #pragma unroll
        for (int m = 0; m < 4; ++m) {
            int p0 = mt * 128 + wm * 64 + m * 16 + lq * 4;
            #pragma unroll
            for (int r = 0; r < 4; ++r) {
                int p  = p0 + r;
                int ni = p / 3136;
                int hw = p - ni * 3136;
                out[(size_t)ni * 802816 + (size_t)ko * 3136 + hw] = acc[m][n][r] * sc;
            }
        }
    }
}

// ---- Fallback: naive direct conv (only if ws too small) ----
__global__ void naive_conv(const float* __restrict__ x, const float* __restrict__ wflat,
                           const float* __restrict__ sf, float* __restrict__ out) {
    int idx = blockIdx.x * 256 + threadIdx.x;
    int w = idx % 56, t = idx / 56;
    int h = t % 56; t /= 56;
    int ko = t % 256; int n = t / 256;
    float acc = 0.f;
    for (int c = 0; c < 256; ++c) {
        const float* xc = x + ((size_t)n * 256 + c) * 3136;
        const float* wc = wflat + ((size_t)ko * 256 + c) * 9;
        #pragma unroll
        for (int r = 0; r < 3; ++r) {
            int hh = h + r - 1;
            if (hh < 0 || hh >= 56) continue;
            #pragma unroll
            for (int s = 0; s < 3; ++s) {
                int ww = w + s - 1;
                if (ww < 0 || ww >= 56) continue;
                float wvv = wc[r * 3 + s];
                float sgn = (wvv > 0.f) ? 1.f : ((wvv < 0.f) ? -1.f : 0.f);
                acc += sgn * xc[hh * 56 + ww];
            }
        }
    }
    out[idx] = acc * sf[ko];
}

extern "C" void kernel_launch(void* const* d_in, const int* in_sizes, int n_in,
                              void* d_out, int out_size, void* d_ws, size_t ws_size,
                              hipStream_t stream) {
    const float* x     = (const float*)d_in[0];
    const float* wflat = (const float*)d_in[1];
    const float* sf    = (const float*)d_in[2];
    float* out = (float*)d_out;

    const size_t need = XP_ELEMS * 2 + WT_ELEMS * 2;
    if (ws_size < need) {
        naive_conv<<<(int)(OUT_ELEMS / 256), 256, 0, stream>>>(x, wflat, sf, out);
        return;
    }
    unsigned short* Xp = (unsigned short*)d_ws;
    unsigned short* Wt = Xp + XP_ELEMS;

    hipMemsetAsync(Xp, 0, XP_ELEMS * 2, stream);        // zero halo (capturable)
    wprep<<<2304, 256, 0, stream>>>(wflat, Wt);
    xprep<<<NIMG * HW, 256, 0, stream>>>(x, Xp);
    bconv_mfma<<<784 * 2, 256, 0, stream>>>(Xp, Wt, sf, out);
}

// Round 4
// 324.035 us; speedup vs baseline: 1.2907x; 1.2907x over previous
//
#include <hip/hip_runtime.h>
#include <hip/hip_bf16.h>
#include <stdint.h>

#define NIMG 32
#define CHN 256
#define HW 56
#define PH 58
#define XP_ELEMS ((size_t)NIMG*PH*PH*CHN)     // 27,557,888 bf16
#define WT_ELEMS ((size_t)9*CHN*CHN)          // 589,824 bf16
#define OUT_ELEMS ((size_t)NIMG*CHN*HW*HW)    // 25,690,112
#define NKT 36                                // K = 2304 = 36 tiles of 64

typedef __attribute__((ext_vector_type(8))) short short8;
typedef __attribute__((ext_vector_type(4))) float floatx4;

#define GLDS(gp, lbyte) __builtin_amdgcn_global_load_lds( \
    (const __attribute__((address_space(1))) void*)(gp), \
    (__attribute__((address_space(3))) void*)((char*)L + (lbyte)), 16, 0, 0)

__device__ inline unsigned short f2bf(float f) {
    union { float f; uint32_t u; } v; v.f = f;
    uint32_t u = v.u;
    return (unsigned short)((u + 0x7FFFu + ((u >> 16) & 1u)) >> 16);  // RNE
}

// ---- weights (flat OIHW fp32) -> sign() bf16, layout [rs][ko][c]; coalesced writes ----
__global__ void wprep(const float* __restrict__ wflat, unsigned short* __restrict__ Wt) {
    int o = blockIdx.x * 256 + threadIdx.x;            // < 589824, output-ordered
    int rs = o >> 16, ko = (o >> 8) & 255, c = o & 255;
    float w = wflat[ko * 2304 + c * 9 + rs];
    Wt[o] = (w > 0.f) ? 0x3F80u : (w < 0.f ? 0xBF80u : 0u);
}

// ---- x NCHW fp32 -> padded NHWC bf16 (halo pre-zeroed by memset) ----
__global__ void xprep(const float* __restrict__ x, unsigned short* __restrict__ Xp) {
    __shared__ unsigned short tile[56 * 264];          // pitch 264 (16B-aligned rows)
    int b = blockIdx.x;                                 // one (n,h) row per block
    int n = b / 56, h = b - n * 56;
    const float* xr = x + ((size_t)n * CHN) * (HW*HW) + h * HW;
    int tid = threadIdx.x;
    #pragma unroll 4
    for (int it = 0; it < 28; ++it) {
        int i = it * 256 + tid;                         // (c2, w): c2<128, w<56
        int c2 = i / 56, w = i - c2 * 56, c = c2 * 2;
        float f0 = xr[(size_t)c * 3136 + w];
        float f1 = xr[(size_t)(c + 1) * 3136 + w];
        uint32_t u = (uint32_t)f2bf(f0) | ((uint32_t)f2bf(f1) << 16);
        *(uint32_t*)&tile[w * 264 + c] = u;             // ~2-way banks: stride 66 words
    }
    __syncthreads();
    unsigned short* op = Xp + (((size_t)n * PH + (h + 1)) * PH + 1) * CHN;
    #pragma unroll
    for (int it = 0; it < 7; ++it) {
        int chunk = it * 256 + tid;
        int w = chunk >> 5, c0 = (chunk & 31) * 8;
        short8 v = *(const short8*)&tile[w * 264 + c0];
        *(short8*)&op[w * 256 + c0] = v;
    }
}

// ---- 256x256 8-phase implicit GEMM (m201-style): BK=64, 8 waves 2Mx4N ----
// LDS: 2 buf x 4 sections (A-lo,A-hi,B-lo,B-hi) x 8192 bf16 = 128 KiB.
// Swizzle: LDS dest linear (global_load_lds), global src slot ^= row&7,
// ds_read applies same XOR -> conflict-free fragment reads (rule 21).
__global__ void __launch_bounds__(512)
bconv8(const unsigned short* __restrict__ Xp, const unsigned short* __restrict__ Wt,
       const float* __restrict__ sf, float* __restrict__ out) {
    extern __shared__ unsigned short L[];
    const int tid  = threadIdx.x;
    const int lane = tid & 63, wv = tid >> 6;
    const int wm = wv >> 2, wn = wv & 3;                // wave grid 2M x 4N
    const int bm = blockIdx.x;                          // 392 M-tiles of 256

    // ---- staging addresses (per thread): 2 lane-loads per half-tile ----
    const int r0 = tid >> 3;                            // row-within-64 block
    const int sx = (tid & 7) ^ (r0 & 7);                // pre-swizzled slot
    uint32_t offA[2][2], offB[2][2];                    // [half][i] byte offsets
    #pragma unroll
    for (int hf = 0; hf < 2; ++hf)
        #pragma unroll
        for (int i = 0; i < 2; ++i) {
            int row = hf * 128 + i * 64 + r0;           // row in 256-tile
            int p = bm * 256 + row;                     // M position
            int n = p / 3136, hwp = p - n * 3136;
            int h = hwp / 56,  w = hwp - h * 56;
            offA[hf][i] = (uint32_t)(((((n * 58 + h) * 58 + w) * 256) + sx * 8) * 2);
            offB[hf][i] = (uint32_t)((row * 256 + sx * 8) * 2);
        }
    const uint32_t ldst0 = (uint32_t)wv * 1024u;        // wave-uniform LDS dest

#define STAGE_A(kt, hf, b) do { \
    int _rs = (kt) >> 2; int _dr = _rs / 3, _dc = _rs - _dr * 3; \
    uint32_t _ko = (uint32_t)((_dr * 58 + _dc) * 512 + ((kt) & 3) * 128); \
    uint32_t _lb = (uint32_t)(((b) * 4 + (hf)) * 16384) + ldst0; \
    GLDS((const char*)Xp + offA[hf][0] + _ko, _lb); \
    GLDS((const char*)Xp + offA[hf][1] + _ko, _lb + 8192u); \
} while (0)

#define STAGE_B(kt, hf, b) do { \
    uint32_t _ko = (uint32_t)((kt) >> 2) * 131072u + (uint32_t)(((kt) & 3) * 128); \
    uint32_t _lb = (uint32_t)(((b) * 4 + 2 + (hf)) * 16384) + ldst0; \
    GLDS((const char*)Wt + offB[hf][0] + _ko, _lb); \
    GLDS((const char*)Wt + offB[hf][1] + _ko, _lb + 8192u); \
} while (0)

    // ---- fragment read offsets (elems) ----
    const int rA = lane & 15, hs = lane >> 4, xm = lane & 7;
    const int sl0 = ((hs)     ^ xm) * 8;                // kk=0 swizzled slot
    const int sl1 = ((4 + hs) ^ xm) * 8;                // kk=1

    floatx4 acc[8][4];
    #pragma unroll
    for (int mf = 0; mf < 8; ++mf)
        #pragma unroll
        for (int nf = 0; nf < 4; ++nf) acc[mf][nf] = (floatx4){0.f, 0.f, 0.f, 0.f};

    // ---- prologue: tile0 full + tile1 A halves ----
    STAGE_A(0, 0, 0); STAGE_A(0, 1, 0); STAGE_B(0, 0, 0); STAGE_B(0, 1, 0);
    STAGE_A(1, 0, 1); STAGE_A(1, 1, 1);
    asm volatile("s_waitcnt vmcnt(4)" ::: "memory");    // tile0 complete
    __builtin_amdgcn_s_barrier();

    short8 a0[4][2], a1[4][2], b0[2][2], b1[2][2];

    for (int j = 0; j < NKT; ++j) {
        const int buf = j & 1, ob = buf ^ 1;
        const uint32_t sA = (uint32_t)(buf * 4 + wm) * 8192u + (uint32_t)(rA * 64);
        const uint32_t sB = (uint32_t)(buf * 4 + 2 + (wn >> 1)) * 8192u
                          + (uint32_t)((wn & 1) * 4096) + (uint32_t)(rA * 64);
        // ---- P0: read A m0 + B n0; stage B-lo(j+1); MFMA (m0,n0) ----
        #pragma unroll
        for (int mf = 0; mf < 4; ++mf) {
            a0[mf][0] = *(const short8*)&L[sA + mf * 1024 + sl0];
            a0[mf][1] = *(const short8*)&L[sA + mf * 1024 + sl1];
        }
        #pragma unroll
        for (int nf = 0; nf < 2; ++nf) {
            b0[nf][0] = *(const short8*)&L[sB + nf * 1024 + sl0];
            b0[nf][1] = *(const short8*)&L[sB + nf * 1024 + sl1];
        }
        if (j < NKT - 1) STAGE_B(j + 1, 0, ob);
        __builtin_amdgcn_s_barrier();
        __builtin_amdgcn_s_setprio(1);
        #pragma unroll
        for (int mf = 0; mf < 4; ++mf)
            #pragma unroll
            for (int nf = 0; nf < 2; ++nf) {
                acc[mf][nf] = __builtin_amdgcn_mfma_f32_16x16x32_bf16(a0[mf][0], b0[nf][0], acc[mf][nf], 0, 0, 0);
                acc[mf][nf] = __builtin_amdgcn_mfma_f32_16x16x32_bf16(a0[mf][1], b0[nf][1], acc[mf][nf], 0, 0, 0);
            }
        __builtin_amdgcn_s_setprio(0);
        __builtin_amdgcn_s_barrier();
        // ---- P1: read A m1; stage B-hi(j+1); MFMA (m1,n0) ----
        #pragma unroll
        for (int mf = 0; mf < 4; ++mf) {
            a1[mf][0] = *(const short8*)&L[sA + (4 + mf) * 1024 + sl0];
            a1[mf][1] = *(const short8*)&L[sA + (4 + mf) * 1024 + sl1];
        }
        if (j < NKT - 1) STAGE_B(j + 1, 1, ob);
        __builtin_amdgcn_s_barrier();
        __builtin_amdgcn_s_setprio(1);
        #pragma unroll
        for (int mf = 0; mf < 4; ++mf)
            #pragma unroll
            for (int nf = 0; nf < 2; ++nf) {
                acc[4 + mf][nf] = __builtin_amdgcn_mfma_f32_16x16x32_bf16(a1[mf][0], b0[nf][0], acc[4 + mf][nf], 0, 0, 0);
                acc[4 + mf][nf] = __builtin_amdgcn_mfma_f32_16x16x32_bf16(a1[mf][1], b0[nf][1], acc[4 + mf][nf], 0, 0, 0);
            }
        __builtin_amdgcn_s_setprio(0);
        __builtin_amdgcn_s_barrier();
        // ---- P2: read B n1; stage A-lo(j+2); MFMA (m0,n1) ----
        #pragma unroll
        for (int nf = 0; nf < 2; ++nf) {
            b1[nf][0] = *(const short8*)&L[sB + (2 + nf) * 1024 + sl0];
            b1[nf][1] = *(const short8*)&L[sB + (2 + nf) * 1024 + sl1];
        }
        if (j < NKT - 2) STAGE_A(j + 2, 0, buf);
        __builtin_amdgcn_s_barrier();
        __builtin_amdgcn_s_setprio(1);
        #pragma unroll
        for (int mf = 0; mf < 4; ++mf)
            #pragma unroll
            for (int nf = 0; nf < 2; ++nf) {
                acc[mf][2 + nf] = __builtin_amdgcn_mfma_f32_16x16x32_bf16(a0[mf][0], b1[nf][0], acc[mf][2 + nf], 0, 0, 0);
                acc[mf][2 + nf] = __builtin_amdgcn_mfma_f32_16x16x32_bf16(a0[mf][1], b1[nf][1], acc[mf][2 + nf], 0, 0, 0);
            }
        __builtin_amdgcn_s_setprio(0);
        __builtin_amdgcn_s_barrier();
        // ---- P3: stage A-hi(j+2); counted vmcnt gate; MFMA (m1,n1) ----
        if (j < NKT - 2) {
            STAGE_A(j + 2, 1, buf);
            asm volatile("s_waitcnt vmcnt(4)" ::: "memory");  // tile j+1 fully resident
        } else {
            asm volatile("s_waitcnt vmcnt(0)" ::: "memory");
        }
        __builtin_amdgcn_s_barrier();
        __builtin_amdgcn_s_setprio(1);
        #pragma unroll
        for (int mf = 0; mf < 4; ++mf)
            #pragma unroll
            for (int nf = 0; nf < 2; ++nf) {
                acc[4 + mf][2 + nf] = __builtin_amdgcn_mfma_f32_16x16x32_bf16(a1[mf][0], b1[nf][0], acc[4 + mf][2 + nf], 0, 0, 0);
                acc[4 + mf][2 + nf] = __builtin_amdgcn_mfma_f32_16x16x32_bf16(a1[mf][1], b1[nf][1], acc[4 + mf][2 + nf], 0, 0, 0);
            }
        __builtin_amdgcn_s_setprio(0);
        __builtin_amdgcn_s_barrier();
    }

    // ---- epilogue: fused per-channel scale, float4 stores to NCHW ----
    const int p00 = bm * 256 + wm * 128 + hs * 4;
    #pragma unroll
    for (int nf = 0; nf < 4; ++nf) {
        int ko = wn * 64 + nf * 16 + rA;
        float sc = sf[ko];
        #pragma unroll
        for (int mf = 0; mf < 8; ++mf) {
            int p = p00 + mf * 16;
            int ni = p / 3136, hwp = p - ni * 3136;
            floatx4 v = acc[mf][nf];
            floatx4 o = {v.x * sc, v.y * sc, v.z * sc, v.w * sc};
            *(floatx4*)&out[(size_t)ni * 802816 + (size_t)ko * 3136 + hwp] = o;
        }
    }
#undef STAGE_A
#undef STAGE_B
}

// ---- Fallback: naive direct conv (only if ws too small) ----
__global__ void naive_conv(const float* __restrict__ x, const float* __restrict__ wflat,
                           const float* __restrict__ sf, float* __restrict__ out) {
    int idx = blockIdx.x * 256 + threadIdx.x;
    int w = idx % 56, t = idx / 56;
    int h = t % 56; t /= 56;
    int ko = t % 256; int n = t / 256;
    float acc = 0.f;
    for (int c = 0; c < 256; ++c) {
        const float* xc = x + ((size_t)n * 256 + c) * 3136;
        const float* wc = wflat + ((size_t)ko * 256 + c) * 9;
        #pragma unroll
        for (int r = 0; r < 3; ++r) {
            int hh = h + r - 1;
            if (hh < 0 || hh >= 56) continue;
            #pragma unroll
            for (int s = 0; s < 3; ++s) {
                int ww = w + s - 1;
                if (ww < 0 || ww >= 56) continue;
                float wvv = wc[r * 3 + s];
                float sgn = (wvv > 0.f) ? 1.f : ((wvv < 0.f) ? -1.f : 0.f);
                acc += sgn * xc[hh * 56 + ww];
            }
        }
    }
    out[idx] = acc * sf[ko];
}

extern "C" void kernel_launch(void* const* d_in, const int* in_sizes, int n_in,
                              void* d_out, int out_size, void* d_ws, size_t ws_size,
                              hipStream_t stream) {
    const float* x     = (const float*)d_in[0];
    const float* wflat = (const float*)d_in[1];
    const float* sf    = (const float*)d_in[2];
    float* out = (float*)d_out;

    const size_t need = XP_ELEMS * 2 + WT_ELEMS * 2;
    if (ws_size < need) {
        naive_conv<<<(int)(OUT_ELEMS / 256), 256, 0, stream>>>(x, wflat, sf, out);
        return;
    }
    unsigned short* Xp = (unsigned short*)d_ws;
    unsigned short* Wt = Xp + XP_ELEMS;

    (void)hipFuncSetAttribute((const void*)bconv8,
                              hipFuncAttributeMaxDynamicSharedMemorySize, 131072);

    hipMemsetAsync(Xp, 0, XP_ELEMS * 2, stream);        // zero halo
    wprep<<<2304, 256, 0, stream>>>(wflat, Wt);
    xprep<<<NIMG * HW, 256, 0, stream>>>(x, Xp);
    bconv8<<<392, 512, 131072, stream>>>(Xp, Wt, sf, out);
}